// Round 2
// baseline (3685.522 us; speedup 1.0000x reference)
//
#include <hip/hip_runtime.h>

#define NNODES 100000
#define NEDGES 800000
// feature dim K = 128 everywhere; hidden 128, out 64

// ---------------------------------------------------------------------------
// Degree: deg[d] += 1 per edge
// ---------------------------------------------------------------------------
__global__ __launch_bounds__(256) void deg_kernel(const int* __restrict__ dst,
                                                  float* __restrict__ deg, int nE) {
    int i = blockIdx.x * 256 + threadIdx.x;
    if (i < nE) atomicAdd(deg + dst[i], 1.0f);
}

// ---------------------------------------------------------------------------
// Scatter-add: sum[dst[e]][:] += h[src[e]][:]  (32 threads/edge, float4 each)
// ---------------------------------------------------------------------------
__global__ __launch_bounds__(256) void scatter_kernel(const float* __restrict__ h,
                                                      const int* __restrict__ src,
                                                      const int* __restrict__ dst,
                                                      float* __restrict__ sum, int nE) {
    long long idx = (long long)blockIdx.x * 256 + threadIdx.x;
    int e = (int)(idx >> 5);
    if (e >= nE) return;
    int c = ((int)idx & 31) << 2;
    int s = src[e], d = dst[e];
    float4 v = *(const float4*)(h + (size_t)s * 128 + c);
    float* o = sum + (size_t)d * 128 + c;
    atomicAdd(o + 0, v.x);
    atomicAdd(o + 1, v.y);
    atomicAdd(o + 2, v.z);
    atomicAdd(o + 3, v.w);
}

// ---------------------------------------------------------------------------
// Combine: out[n][:] = base[n][:] + sum[n][:] / max(deg[n],1)   (float4/thread)
// ---------------------------------------------------------------------------
__global__ __launch_bounds__(256) void combine_kernel(const float* __restrict__ base,
                                                      const float* __restrict__ sum,
                                                      const float* __restrict__ deg,
                                                      float* __restrict__ out, int n) {
    long long idx = (long long)blockIdx.x * 256 + threadIdx.x;
    int node = (int)(idx >> 5);
    if (node >= n) return;
    int c = ((int)idx & 31) << 2;
    float r = 1.0f / fmaxf(deg[node], 1.0f);
    float4 bs = *(const float4*)(base + (size_t)node * 128 + c);
    float4 sm = *(const float4*)(sum + (size_t)node * 128 + c);
    float4 o;
    o.x = bs.x + sm.x * r;
    o.y = bs.y + sm.y * r;
    o.z = bs.z + sm.z * r;
    o.w = bs.w + sm.w * r;
    *(float4*)(out + (size_t)node * 128 + c) = o;
}

// ---------------------------------------------------------------------------
// Linear: out[M,BN] = act(in[M,128] @ W[BN,128]^T + b)
// BM=64, BK=32, 256 threads as 16x16, thread tile 4 x TN (TN = BN/16)
// LDS pad 33: a-reads broadcast (free), b-reads 4-way (~1.58x) — baseline OK
// ---------------------------------------------------------------------------
template <int BN, int TN, bool RELU>
__global__ __launch_bounds__(256) void lin_kernel(const float* __restrict__ in,
                                                  const float* __restrict__ W,
                                                  const float* __restrict__ bias,
                                                  float* __restrict__ out, int M) {
    __shared__ float xs[64][33];
    __shared__ float ws[BN][33];
    const int tid = threadIdx.x;
    const int ty = tid >> 4, tx = tid & 15;
    const int r0 = blockIdx.x * 64;

    float acc[4][TN];
#pragma unroll
    for (int n = 0; n < TN; ++n) {
        float bv = bias[tx * TN + n];
#pragma unroll
        for (int m = 0; m < 4; ++m) acc[m][n] = bv;
    }

    for (int kc = 0; kc < 128; kc += 32) {
        __syncthreads();
        // stage x tile: 64 rows x 32 cols = 512 float4
#pragma unroll
        for (int i = 0; i < 2; ++i) {
            int id = tid + i * 256;
            int row = id >> 3, c4 = (id & 7) << 2;
            float4 v = make_float4(0.f, 0.f, 0.f, 0.f);
            int gr = r0 + row;
            if (gr < M) v = *(const float4*)(in + (size_t)gr * 128 + kc + c4);
            xs[row][c4 + 0] = v.x;
            xs[row][c4 + 1] = v.y;
            xs[row][c4 + 2] = v.z;
            xs[row][c4 + 3] = v.w;
        }
        // stage W tile: BN rows x 32 cols
#pragma unroll
        for (int i = 0; i < BN / 32; ++i) {
            int id = tid + i * 256;
            int row = id >> 3, c4 = (id & 7) << 2;
            float4 v = *(const float4*)(W + (size_t)row * 128 + kc + c4);
            ws[row][c4 + 0] = v.x;
            ws[row][c4 + 1] = v.y;
            ws[row][c4 + 2] = v.z;
            ws[row][c4 + 3] = v.w;
        }
        __syncthreads();
#pragma unroll
        for (int k = 0; k < 32; ++k) {
            float a[4], bb[TN];
#pragma unroll
            for (int m = 0; m < 4; ++m) a[m] = xs[ty * 4 + m][k];
#pragma unroll
            for (int n = 0; n < TN; ++n) bb[n] = ws[tx * TN + n][k];
#pragma unroll
            for (int m = 0; m < 4; ++m)
#pragma unroll
                for (int n = 0; n < TN; ++n) acc[m][n] = fmaf(a[m], bb[n], acc[m][n]);
        }
    }

#pragma unroll
    for (int m = 0; m < 4; ++m) {
        int gr = r0 + ty * 4 + m;
        if (gr >= M) continue;
#pragma unroll
        for (int n4 = 0; n4 < TN; n4 += 4) {
            float4 v;
            v.x = acc[m][n4 + 0];
            v.y = acc[m][n4 + 1];
            v.z = acc[m][n4 + 2];
            v.w = acc[m][n4 + 3];
            if (RELU) {
                v.x = fmaxf(v.x, 0.f);
                v.y = fmaxf(v.y, 0.f);
                v.z = fmaxf(v.z, 0.f);
                v.w = fmaxf(v.w, 0.f);
            }
            *(float4*)(out + (size_t)gr * BN + tx * TN + n4) = v;
        }
    }
}

// ---------------------------------------------------------------------------
extern "C" void kernel_launch(void* const* d_in, const int* in_sizes, int n_in,
                              void* d_out, int out_size, void* d_ws, size_t ws_size,
                              hipStream_t stream) {
    const float* x   = (const float*)d_in[0];
    const int*   src = (const int*)d_in[1];
    const int*   dst = (const int*)d_in[2];
    const float* W1  = (const float*)d_in[3];
    const float* b1  = (const float*)d_in[4];
    const float* W2  = (const float*)d_in[5];
    const float* b2  = (const float*)d_in[6];
    const float* W3  = (const float*)d_in[7];
    const float* b3  = (const float*)d_in[8];
    const float* Wo1 = (const float*)d_in[9];
    const float* bo1 = (const float*)d_in[10];
    const float* Wo2 = (const float*)d_in[11];
    const float* bo2 = (const float*)d_in[12];
    float* out = (float*)d_out;

    const size_t FEAT_BYTES = (size_t)NNODES * 128 * sizeof(float);  // 51.2 MB
    char* ws = (char*)d_ws;
    float* A   = (float*)ws;
    float* B   = (float*)(ws + FEAT_BYTES);
    float* deg = (float*)(ws + 2 * FEAT_BYTES);

    dim3 blk(256);
    const int gl = (NNODES + 63) / 64;                 // 1563
    const int ge = (NEDGES + 255) / 256;               // deg grid
    const int gs = (int)(((long long)NEDGES * 32) / 256);  // 100000
    const int gc = (int)(((long long)NNODES * 32 + 255) / 256);

    // degree (shared by both aggregations)
    hipMemsetAsync(deg, 0, NNODES * sizeof(float), stream);
    deg_kernel<<<ge, blk, 0, stream>>>(dst, deg, NEDGES);

    // x2 = lin2(relu(lin1(x)))
    lin_kernel<128, 8, true ><<<gl, blk, 0, stream>>>(x, W1, b1, A, NNODES);
    lin_kernel<128, 8, false><<<gl, blk, 0, stream>>>(A, W2, b2, B, NNODES);

    // h = x2 + mean_agg(x2)
    hipMemsetAsync(A, 0, FEAT_BYTES, stream);
    scatter_kernel<<<gs, blk, 0, stream>>>(B, src, dst, A, NEDGES);
    combine_kernel<<<gc, blk, 0, stream>>>(B, A, deg, A, NNODES);

    // h = lin2(relu(lin1(h)))
    lin_kernel<128, 8, true ><<<gl, blk, 0, stream>>>(A, W1, b1, B, NNODES);
    lin_kernel<128, 8, false><<<gl, blk, 0, stream>>>(B, W2, b2, A, NNODES);
    // h3 = relu(lin3(h))
    lin_kernel<128, 8, true ><<<gl, blk, 0, stream>>>(A, W3, b3, B, NNODES);

    // h4 = h3 + mean_agg(h3)
    hipMemsetAsync(A, 0, FEAT_BYTES, stream);
    scatter_kernel<<<gs, blk, 0, stream>>>(B, src, dst, A, NEDGES);
    combine_kernel<<<gc, blk, 0, stream>>>(B, A, deg, A, NNODES);

    // h5 = relu(lin3(h4)); h6 = relu(lino1(h5)); out = lino2(h6)
    lin_kernel<128, 8, true ><<<gl, blk, 0, stream>>>(A, W3, b3, B, NNODES);
    lin_kernel<128, 8, true ><<<gl, blk, 0, stream>>>(B, Wo1, bo1, A, NNODES);
    lin_kernel<64, 4, false><<<gl, blk, 0, stream>>>(A, Wo2, bo2, out, NNODES);
}

// Round 3
// 1092.230 us; speedup vs baseline: 3.3743x; 3.3743x over previous
//
#include <hip/hip_runtime.h>

#define NNODES 100000
#define NEDGES 800000
// feature dim 128 everywhere except final out 64

// ===========================================================================
// CSR build: histogram -> 3-kernel exclusive scan -> bucket fill
// ===========================================================================
__global__ __launch_bounds__(256) void hist_kernel(const int* __restrict__ dst,
                                                   int* __restrict__ counts, int nE) {
    int i = blockIdx.x * 256 + threadIdx.x;
    if (i < nE) atomicAdd(counts + dst[i], 1);
}

// block sums (256 elems per block)
__global__ __launch_bounds__(256) void scan1_kernel(const int* __restrict__ counts,
                                                    int* __restrict__ bsum, int n) {
    __shared__ int s[256];
    int i = blockIdx.x * 256 + threadIdx.x;
    s[threadIdx.x] = (i < n) ? counts[i] : 0;
    __syncthreads();
    for (int off = 128; off > 0; off >>= 1) {
        if (threadIdx.x < off) s[threadIdx.x] += s[threadIdx.x + off];
        __syncthreads();
    }
    if (threadIdx.x == 0) bsum[blockIdx.x] = s[0];
}

// exclusive scan of block sums (single block, nb <= 512)
__global__ __launch_bounds__(512) void scan2_kernel(int* __restrict__ bsum, int nb) {
    __shared__ int s[512];
    int t = threadIdx.x;
    int orig = (t < nb) ? bsum[t] : 0;
    s[t] = orig;
    __syncthreads();
    for (int off = 1; off < 512; off <<= 1) {
        int v = (t >= off) ? s[t - off] : 0;
        __syncthreads();
        s[t] += v;
        __syncthreads();
    }
    if (t < nb) bsum[t] = s[t] - orig;  // exclusive
}

// per-block exclusive scan + block offset -> rowptr
__global__ __launch_bounds__(256) void scan3_kernel(const int* __restrict__ counts,
                                                    const int* __restrict__ boff,
                                                    int* __restrict__ rowptr, int n) {
    __shared__ int s[256];
    int i = blockIdx.x * 256 + threadIdx.x;
    int t = threadIdx.x;
    int orig = (i < n) ? counts[i] : 0;
    s[t] = orig;
    __syncthreads();
    for (int off = 1; off < 256; off <<= 1) {
        int v = (t >= off) ? s[t - off] : 0;
        __syncthreads();
        s[t] += v;
        __syncthreads();
    }
    if (i < n) rowptr[i] = boff[blockIdx.x] + s[t] - orig;
    if (i == n - 1) rowptr[n] = boff[blockIdx.x] + s[t];  // total
}

__global__ __launch_bounds__(256) void fill_kernel(const int* __restrict__ src,
                                                   const int* __restrict__ dst,
                                                   const int* __restrict__ rowptr,
                                                   int* __restrict__ cur,
                                                   int* __restrict__ eidx, int nE) {
    int i = blockIdx.x * 256 + threadIdx.x;
    if (i >= nE) return;
    int d = dst[i];
    int p = atomicAdd(cur + d, 1);
    eidx[rowptr[d] + p] = src[i];
}

// ===========================================================================
// Fused gather-mean + combine: out[n] = base[n] + mean_{e: dst=n} h[src[e]]
// one wave per node; lane owns 2 columns (float2, 512B/row coalesced)
// ===========================================================================
__global__ __launch_bounds__(256) void gather_mean_kernel(const float* h,
                                                          const float* base,
                                                          const int* __restrict__ rowptr,
                                                          const int* __restrict__ eidx,
                                                          float* __restrict__ out, int n) {
    int node = blockIdx.x * 4 + (threadIdx.x >> 6);
    int lane = threadIdx.x & 63;
    if (node >= n) return;
    int e0 = rowptr[node], e1 = rowptr[node + 1];
    float ax = 0.f, ay = 0.f;
    for (int j = e0; j < e1; j += 64) {
        int m = min(64, e1 - j);
        int sid = (lane < m) ? eidx[j + lane] : 0;
        for (int t = 0; t < m; ++t) {
            int s = __shfl(sid, t);
            float2 v = *(const float2*)(h + (size_t)s * 128 + lane * 2);
            ax += v.x;
            ay += v.y;
        }
    }
    float r = 1.0f / fmaxf((float)(e1 - e0), 1.0f);
    float2 b = *(const float2*)(base + (size_t)node * 128 + lane * 2);
    float2 o;
    o.x = b.x + ax * r;
    o.y = b.y + ay * r;
    *(float2*)(out + (size_t)node * 128 + lane * 2) = o;
}

// ===========================================================================
// Linear: out[M,BN] = act(in[M,128] @ W[BN,128]^T + b)   (unchanged fp32)
// ===========================================================================
template <int BN, int TN, bool RELU>
__global__ __launch_bounds__(256) void lin_kernel(const float* __restrict__ in,
                                                  const float* __restrict__ W,
                                                  const float* __restrict__ bias,
                                                  float* __restrict__ out, int M) {
    __shared__ float xs[64][33];
    __shared__ float ws[BN][33];
    const int tid = threadIdx.x;
    const int ty = tid >> 4, tx = tid & 15;
    const int r0 = blockIdx.x * 64;

    float acc[4][TN];
#pragma unroll
    for (int n = 0; n < TN; ++n) {
        float bv = bias[tx * TN + n];
#pragma unroll
        for (int m = 0; m < 4; ++m) acc[m][n] = bv;
    }

    for (int kc = 0; kc < 128; kc += 32) {
        __syncthreads();
#pragma unroll
        for (int i = 0; i < 2; ++i) {
            int id = tid + i * 256;
            int row = id >> 3, c4 = (id & 7) << 2;
            float4 v = make_float4(0.f, 0.f, 0.f, 0.f);
            int gr = r0 + row;
            if (gr < M) v = *(const float4*)(in + (size_t)gr * 128 + kc + c4);
            xs[row][c4 + 0] = v.x;
            xs[row][c4 + 1] = v.y;
            xs[row][c4 + 2] = v.z;
            xs[row][c4 + 3] = v.w;
        }
#pragma unroll
        for (int i = 0; i < BN / 32; ++i) {
            int id = tid + i * 256;
            int row = id >> 3, c4 = (id & 7) << 2;
            float4 v = *(const float4*)(W + (size_t)row * 128 + kc + c4);
            ws[row][c4 + 0] = v.x;
            ws[row][c4 + 1] = v.y;
            ws[row][c4 + 2] = v.z;
            ws[row][c4 + 3] = v.w;
        }
        __syncthreads();
#pragma unroll
        for (int k = 0; k < 32; ++k) {
            float a[4], bb[TN];
#pragma unroll
            for (int m = 0; m < 4; ++m) a[m] = xs[ty * 4 + m][k];
#pragma unroll
            for (int n = 0; n < TN; ++n) bb[n] = ws[tx * TN + n][k];
#pragma unroll
            for (int m = 0; m < 4; ++m)
#pragma unroll
                for (int n = 0; n < TN; ++n) acc[m][n] = fmaf(a[m], bb[n], acc[m][n]);
        }
    }

#pragma unroll
    for (int m = 0; m < 4; ++m) {
        int gr = r0 + ty * 4 + m;
        if (gr >= M) continue;
#pragma unroll
        for (int n4 = 0; n4 < TN; n4 += 4) {
            float4 v;
            v.x = acc[m][n4 + 0];
            v.y = acc[m][n4 + 1];
            v.z = acc[m][n4 + 2];
            v.w = acc[m][n4 + 3];
            if (RELU) {
                v.x = fmaxf(v.x, 0.f);
                v.y = fmaxf(v.y, 0.f);
                v.z = fmaxf(v.z, 0.f);
                v.w = fmaxf(v.w, 0.f);
            }
            *(float4*)(out + (size_t)gr * BN + tx * TN + n4) = v;
        }
    }
}

// ===========================================================================
extern "C" void kernel_launch(void* const* d_in, const int* in_sizes, int n_in,
                              void* d_out, int out_size, void* d_ws, size_t ws_size,
                              hipStream_t stream) {
    const float* x   = (const float*)d_in[0];
    const int*   src = (const int*)d_in[1];
    const int*   dst = (const int*)d_in[2];
    const float* W1  = (const float*)d_in[3];
    const float* b1  = (const float*)d_in[4];
    const float* W2  = (const float*)d_in[5];
    const float* b2  = (const float*)d_in[6];
    const float* W3  = (const float*)d_in[7];
    const float* b3  = (const float*)d_in[8];
    const float* Wo1 = (const float*)d_in[9];
    const float* bo1 = (const float*)d_in[10];
    const float* Wo2 = (const float*)d_in[11];
    const float* bo2 = (const float*)d_in[12];
    float* out = (float*)d_out;

    const size_t FEAT_BYTES = (size_t)NNODES * 128 * sizeof(float);  // 51.2 MB
    char* ws = (char*)d_ws;
    float* A      = (float*)ws;
    float* B      = (float*)(ws + FEAT_BYTES);
    char*  p      = ws + 2 * FEAT_BYTES;
    int*   counts = (int*)p;              p += 512 * 1024;
    int*   rowptr = (int*)p;              p += 512 * 1024;
    int*   cur    = (int*)p;              p += 512 * 1024;
    int*   bsum   = (int*)p;              p += 16 * 1024;
    int*   eidx   = (int*)p;              // 3.2 MB

    dim3 blk(256);
    const int NB   = (NNODES + 255) / 256;   // scan blocks = 391
    const int ge   = (NEDGES + 255) / 256;
    const int gl   = (NNODES + 63) / 64;     // lin grid
    const int gg   = (NNODES + 3) / 4;       // gather grid (4 waves/block)

    // ---- CSR build (dst-indexed) ----
    hipMemsetAsync(counts, 0, NNODES * sizeof(int), stream);
    hist_kernel<<<ge, blk, 0, stream>>>(dst, counts, NEDGES);
    scan1_kernel<<<NB, blk, 0, stream>>>(counts, bsum, NNODES);
    scan2_kernel<<<1, 512, 0, stream>>>(bsum, NB);
    scan3_kernel<<<NB, blk, 0, stream>>>(counts, bsum, rowptr, NNODES);
    hipMemsetAsync(cur, 0, NNODES * sizeof(int), stream);
    fill_kernel<<<ge, blk, 0, stream>>>(src, dst, rowptr, cur, eidx, NEDGES);

    // ---- x2 = lin2(relu(lin1(x))) ----
    lin_kernel<128, 8, true ><<<gl, blk, 0, stream>>>(x, W1, b1, A, NNODES);
    lin_kernel<128, 8, false><<<gl, blk, 0, stream>>>(A, W2, b2, B, NNODES);

    // ---- h = x2 + mean_agg(x2) ----
    gather_mean_kernel<<<gg, blk, 0, stream>>>(B, B, rowptr, eidx, A, NNODES);

    // ---- h = lin2(relu(lin1(h))); h3 = relu(lin3(h)) ----
    lin_kernel<128, 8, true ><<<gl, blk, 0, stream>>>(A, W1, b1, B, NNODES);
    lin_kernel<128, 8, false><<<gl, blk, 0, stream>>>(B, W2, b2, A, NNODES);
    lin_kernel<128, 8, true ><<<gl, blk, 0, stream>>>(A, W3, b3, B, NNODES);

    // ---- h4 = h3 + mean_agg(h3) ----
    gather_mean_kernel<<<gg, blk, 0, stream>>>(B, B, rowptr, eidx, A, NNODES);

    // ---- h5 = relu(lin3(h4)); h6 = relu(lino1(h5)); out = lino2(h6) ----
    lin_kernel<128, 8, true ><<<gl, blk, 0, stream>>>(A, W3, b3, B, NNODES);
    lin_kernel<128, 8, true ><<<gl, blk, 0, stream>>>(B, Wo1, bo1, A, NNODES);
    lin_kernel<64, 4, false><<<gl, blk, 0, stream>>>(A, Wo2, bo2, out, NNODES);
}

// Round 4
// 640.819 us; speedup vs baseline: 5.7513x; 1.7044x over previous
//
#include <hip/hip_runtime.h>

#define NNODES 100000
#define NEDGES 800000
#define NTILES (NNODES / 16)   // 6250, exact

typedef __bf16 bf16x8 __attribute__((ext_vector_type(8)));
typedef __bf16 bf16x4 __attribute__((ext_vector_type(4)));
typedef __bf16 bf16x2 __attribute__((ext_vector_type(2)));
typedef float f32x4 __attribute__((ext_vector_type(4)));

// ===========================================================================
// fp32 -> (hi, lo) bf16 split: x ≈ hi + lo, |residual| ~ 2^-17 |x|
// ===========================================================================
__global__ __launch_bounds__(256) void split_kernel(const float* __restrict__ in,
                                                    __bf16* __restrict__ hi,
                                                    __bf16* __restrict__ lo, int n4) {
    int i = blockIdx.x * 256 + threadIdx.x;
    if (i >= n4) return;
    float4 v = ((const float4*)in)[i];
    __bf16 h0 = (__bf16)v.x; __bf16 l0 = (__bf16)(v.x - (float)h0);
    __bf16 h1 = (__bf16)v.y; __bf16 l1 = (__bf16)(v.y - (float)h1);
    __bf16 h2 = (__bf16)v.z; __bf16 l2 = (__bf16)(v.z - (float)h2);
    __bf16 h3 = (__bf16)v.w; __bf16 l3 = (__bf16)(v.w - (float)h3);
    bf16x4 hv = {h0, h1, h2, h3};
    bf16x4 lv = {l0, l1, l2, l3};
    ((bf16x4*)hi)[i] = hv;
    ((bf16x4*)lo)[i] = lv;
}

// ===========================================================================
// CSR build: histogram -> 3-kernel exclusive scan -> bucket fill (round-3 proven)
// ===========================================================================
__global__ __launch_bounds__(256) void hist_kernel(const int* __restrict__ dst,
                                                   int* __restrict__ counts, int nE) {
    int i = blockIdx.x * 256 + threadIdx.x;
    if (i < nE) atomicAdd(counts + dst[i], 1);
}

__global__ __launch_bounds__(256) void scan1_kernel(const int* __restrict__ counts,
                                                    int* __restrict__ bsum, int n) {
    __shared__ int s[256];
    int i = blockIdx.x * 256 + threadIdx.x;
    s[threadIdx.x] = (i < n) ? counts[i] : 0;
    __syncthreads();
    for (int off = 128; off > 0; off >>= 1) {
        if (threadIdx.x < off) s[threadIdx.x] += s[threadIdx.x + off];
        __syncthreads();
    }
    if (threadIdx.x == 0) bsum[blockIdx.x] = s[0];
}

__global__ __launch_bounds__(512) void scan2_kernel(int* __restrict__ bsum, int nb) {
    __shared__ int s[512];
    int t = threadIdx.x;
    int orig = (t < nb) ? bsum[t] : 0;
    s[t] = orig;
    __syncthreads();
    for (int off = 1; off < 512; off <<= 1) {
        int v = (t >= off) ? s[t - off] : 0;
        __syncthreads();
        s[t] += v;
        __syncthreads();
    }
    if (t < nb) bsum[t] = s[t] - orig;  // exclusive
}

__global__ __launch_bounds__(256) void scan3_kernel(const int* __restrict__ counts,
                                                    const int* __restrict__ boff,
                                                    int* __restrict__ rowptr, int n) {
    __shared__ int s[256];
    int i = blockIdx.x * 256 + threadIdx.x;
    int t = threadIdx.x;
    int orig = (i < n) ? counts[i] : 0;
    s[t] = orig;
    __syncthreads();
    for (int off = 1; off < 256; off <<= 1) {
        int v = (t >= off) ? s[t - off] : 0;
        __syncthreads();
        s[t] += v;
        __syncthreads();
    }
    if (i < n) rowptr[i] = boff[blockIdx.x] + s[t] - orig;
    if (i == n - 1) rowptr[n] = boff[blockIdx.x] + s[t];
}

__global__ __launch_bounds__(256) void fill_kernel(const int* __restrict__ src,
                                                   const int* __restrict__ dst,
                                                   const int* __restrict__ rowptr,
                                                   int* __restrict__ cur,
                                                   int* __restrict__ eidx, int nE) {
    int i = blockIdx.x * 256 + threadIdx.x;
    if (i >= nE) return;
    int d = dst[i];
    int p = atomicAdd(cur + d, 1);
    eidx[rowptr[d] + p] = src[i];
}

// ===========================================================================
// Fused gather-mean + combine, bf16-plane I/O.
// out = (base_hi+base_lo) + mean_{nbr} hi(nbr); result re-split to hi/lo.
// One wave per node; lane owns cols {2*lane, 2*lane+1}.
// ===========================================================================
__global__ __launch_bounds__(256) void gather_kernel(const __bf16* __restrict__ Hhi,
                                                     const __bf16* __restrict__ Hlo,
                                                     const int* __restrict__ rowptr,
                                                     const int* __restrict__ eidx,
                                                     __bf16* __restrict__ Ohi,
                                                     __bf16* __restrict__ Olo, int n) {
    int node = blockIdx.x * 4 + (threadIdx.x >> 6);
    int lane = threadIdx.x & 63;
    if (node >= n) return;
    int e0 = rowptr[node], e1 = rowptr[node + 1];
    float ax = 0.f, ay = 0.f;
    for (int j = e0; j < e1; j += 64) {
        int mm = min(64, e1 - j);
        int sid = (lane < mm) ? eidx[j + lane] : 0;
        for (int t = 0; t < mm; ++t) {
            int s = __shfl(sid, t);
            bf16x2 v = *(const bf16x2*)(Hhi + (size_t)s * 128 + lane * 2);
            ax += (float)v.x;
            ay += (float)v.y;
        }
    }
    float r = 1.0f / fmaxf((float)(e1 - e0), 1.0f);
    bf16x2 bh = *(const bf16x2*)(Hhi + (size_t)node * 128 + lane * 2);
    bf16x2 bl = *(const bf16x2*)(Hlo + (size_t)node * 128 + lane * 2);
    float ox = (float)bh.x + (float)bl.x + ax * r;
    float oy = (float)bh.y + (float)bl.y + ay * r;
    __bf16 h0 = (__bf16)ox; __bf16 l0 = (__bf16)(ox - (float)h0);
    __bf16 h1 = (__bf16)oy; __bf16 l1 = (__bf16)(oy - (float)h1);
    bf16x2 ho = {h0, h1}, lv = {l0, l1};
    *(bf16x2*)(Ohi + (size_t)node * 128 + lane * 2) = ho;
    *(bf16x2*)(Olo + (size_t)node * 128 + lane * 2) = lv;
}

// ===========================================================================
// Split-bf16 MFMA GEMM: out[M,N] = act(in[M,128] @ W[N,128]^T + b)
// Fragment layout (16x16x32): A: row=l&15, k-slot=(l>>4)*8+j ; B mirrored
// (col=l&15). A/B use the SAME (group,elem)->k map, so the contraction is
// invariant to the HW's internal k permutation. C/D: col=l&15,
// row=(l>>4)*4+reg  [verified m89/m91].
// One wave = one 16-row M-tile x N cols; W-frags register-resident across a
// grid-stride tile loop; no LDS, no barriers.
// ===========================================================================
template <int NT, bool RELU, bool OUTF32>
__global__ __launch_bounds__(256) void gemm_kernel(const __bf16* __restrict__ Ahi,
                                                   const __bf16* __restrict__ Alo,
                                                   const __bf16* __restrict__ Whi,
                                                   const __bf16* __restrict__ Wlo,
                                                   const float* __restrict__ bias,
                                                   __bf16* __restrict__ Ohi,
                                                   __bf16* __restrict__ Olo,
                                                   float* __restrict__ Of32, int ntiles) {
    constexpr int N = NT * 4 * 16;  // 128 or 64
    const int lane = threadIdx.x & 63;
    const int wave = threadIdx.x >> 6;
    const int lm = lane & 15;
    const int lk = (lane >> 4) * 8;

    bf16x8 bhi[NT][4], blo[NT][4];
    float bval[NT];
#pragma unroll
    for (int t = 0; t < NT; ++t) {
        const int n = (wave * NT + t) * 16 + lm;
        bval[t] = bias[n];
#pragma unroll
        for (int ks = 0; ks < 4; ++ks) {
            const int off = n * 128 + ks * 32 + lk;
            bhi[t][ks] = *(const bf16x8*)(Whi + off);
            blo[t][ks] = *(const bf16x8*)(Wlo + off);
        }
    }

    for (int tile = blockIdx.x; tile < ntiles; tile += gridDim.x) {
        const size_t abase = (size_t)(tile * 16 + lm) * 128;
        bf16x8 ahi[4], alo[4];
#pragma unroll
        for (int ks = 0; ks < 4; ++ks) {
            ahi[ks] = *(const bf16x8*)(Ahi + abase + ks * 32 + lk);
            alo[ks] = *(const bf16x8*)(Alo + abase + ks * 32 + lk);
        }
#pragma unroll
        for (int t = 0; t < NT; ++t) {
            f32x4 acc = {bval[t], bval[t], bval[t], bval[t]};
#pragma unroll
            for (int ks = 0; ks < 4; ++ks) {
                acc = __builtin_amdgcn_mfma_f32_16x16x32_bf16(ahi[ks], bhi[t][ks], acc, 0, 0, 0);
                acc = __builtin_amdgcn_mfma_f32_16x16x32_bf16(alo[ks], bhi[t][ks], acc, 0, 0, 0);
                acc = __builtin_amdgcn_mfma_f32_16x16x32_bf16(ahi[ks], blo[t][ks], acc, 0, 0, 0);
            }
            const int n = (wave * NT + t) * 16 + lm;
#pragma unroll
            for (int r = 0; r < 4; ++r) {
                const size_t m = (size_t)tile * 16 + (lane >> 4) * 4 + r;
                float v = acc[r];
                if (RELU) v = fmaxf(v, 0.f);
                if (OUTF32) {
                    Of32[m * N + n] = v;
                } else {
                    __bf16 h = (__bf16)v;
                    __bf16 l = (__bf16)(v - (float)h);
                    Ohi[m * 128 + n] = h;
                    Olo[m * 128 + n] = l;
                }
            }
        }
    }
}

// ===========================================================================
extern "C" void kernel_launch(void* const* d_in, const int* in_sizes, int n_in,
                              void* d_out, int out_size, void* d_ws, size_t ws_size,
                              hipStream_t stream) {
    const float* x   = (const float*)d_in[0];
    const int*   src = (const int*)d_in[1];
    const int*   dst = (const int*)d_in[2];
    const float* W1  = (const float*)d_in[3];
    const float* b1  = (const float*)d_in[4];
    const float* W2  = (const float*)d_in[5];
    const float* b2  = (const float*)d_in[6];
    const float* W3  = (const float*)d_in[7];
    const float* b3  = (const float*)d_in[8];
    const float* Wo1 = (const float*)d_in[9];
    const float* bo1 = (const float*)d_in[10];
    const float* Wo2 = (const float*)d_in[11];
    const float* bo2 = (const float*)d_in[12];
    float* out = (float*)d_out;

    const size_t PLANE = (size_t)NNODES * 128 * sizeof(__bf16);  // 25.6 MB
    char* ws = (char*)d_ws;
    __bf16* P0h = (__bf16*)ws;
    __bf16* P0l = (__bf16*)(ws + PLANE);
    __bf16* P1h = (__bf16*)(ws + 2 * PLANE);
    __bf16* P1l = (__bf16*)(ws + 3 * PLANE);
    char* p = ws + 4 * PLANE;
    __bf16* WH = (__bf16*)p;  p += 256 * 1024;   // 73728 elems packed
    __bf16* WL = (__bf16*)p;  p += 256 * 1024;
    int* counts = (int*)p;    p += 512 * 1024;
    int* rowptr = (int*)p;    p += 512 * 1024;
    int* cur    = (int*)p;    p += 512 * 1024;
    int* bsum   = (int*)p;    p += 16 * 1024;
    int* eidx   = (int*)p;    // 3.2 MB

    const int OW1 = 0, OW2 = 16384, OW3 = 32768, OWo1 = 49152, OWo2 = 65536;

    dim3 blk(256);
    const int NB = (NNODES + 255) / 256;  // 391
    const int ge = (NEDGES + 255) / 256;
    const int gg = (NNODES + 3) / 4;      // gather grid
    const int GB = 1024;                  // gemm grid: 4 blocks/CU resident

    // ---- input & weight hi/lo splits ----
    split_kernel<<<12500, blk, 0, stream>>>(x, P0h, P0l, NNODES * 128 / 4);
    split_kernel<<<16, blk, 0, stream>>>(W1,  WH + OW1,  WL + OW1,  4096);
    split_kernel<<<16, blk, 0, stream>>>(W2,  WH + OW2,  WL + OW2,  4096);
    split_kernel<<<16, blk, 0, stream>>>(W3,  WH + OW3,  WL + OW3,  4096);
    split_kernel<<<16, blk, 0, stream>>>(Wo1, WH + OWo1, WL + OWo1, 4096);
    split_kernel<<<8,  blk, 0, stream>>>(Wo2, WH + OWo2, WL + OWo2, 2048);

    // ---- CSR build (dst-indexed) ----
    hipMemsetAsync(counts, 0, NNODES * sizeof(int), stream);
    hist_kernel<<<ge, blk, 0, stream>>>(dst, counts, NEDGES);
    scan1_kernel<<<NB, blk, 0, stream>>>(counts, bsum, NNODES);
    scan2_kernel<<<1, 512, 0, stream>>>(bsum, NB);
    scan3_kernel<<<NB, blk, 0, stream>>>(counts, bsum, rowptr, NNODES);
    hipMemsetAsync(cur, 0, NNODES * sizeof(int), stream);
    fill_kernel<<<ge, blk, 0, stream>>>(src, dst, rowptr, cur, eidx, NEDGES);

    // ---- x2 = lin2(relu(lin1(x))) ----
    gemm_kernel<2, true,  false><<<GB, blk, 0, stream>>>(P0h, P0l, WH + OW1, WL + OW1, b1, P1h, P1l, nullptr, NTILES);
    gemm_kernel<2, false, false><<<GB, blk, 0, stream>>>(P1h, P1l, WH + OW2, WL + OW2, b2, P0h, P0l, nullptr, NTILES);

    // ---- h = x2 + mean_agg(x2) ----
    gather_kernel<<<gg, blk, 0, stream>>>(P0h, P0l, rowptr, eidx, P1h, P1l, NNODES);

    // ---- h = lin2(relu(lin1(h))); h3 = relu(lin3(h)) ----
    gemm_kernel<2, true,  false><<<GB, blk, 0, stream>>>(P1h, P1l, WH + OW1, WL + OW1, b1, P0h, P0l, nullptr, NTILES);
    gemm_kernel<2, false, false><<<GB, blk, 0, stream>>>(P0h, P0l, WH + OW2, WL + OW2, b2, P1h, P1l, nullptr, NTILES);
    gemm_kernel<2, true,  false><<<GB, blk, 0, stream>>>(P1h, P1l, WH + OW3, WL + OW3, b3, P0h, P0l, nullptr, NTILES);

    // ---- h4 = h3 + mean_agg(h3) ----
    gather_kernel<<<gg, blk, 0, stream>>>(P0h, P0l, rowptr, eidx, P1h, P1l, NNODES);

    // ---- h5 = relu(lin3(h4)); h6 = relu(lino1(h5)); out = lino2(h6) ----
    gemm_kernel<2, true,  false><<<GB, blk, 0, stream>>>(P1h, P1l, WH + OW3, WL + OW3, b3, P0h, P0l, nullptr, NTILES);
    gemm_kernel<2, true,  false><<<GB, blk, 0, stream>>>(P0h, P0l, WH + OWo1, WL + OWo1, bo1, P1h, P1l, nullptr, NTILES);
    gemm_kernel<1, false, true ><<<GB, blk, 0, stream>>>(P1h, P1l, WH + OWo2, WL + OWo2, bo2, nullptr, nullptr, out, NTILES);
}

// Round 5
// 625.638 us; speedup vs baseline: 5.8908x; 1.0243x over previous
//
#include <hip/hip_runtime.h>

#define NNODES 100000
#define NEDGES 800000
#define NT32   (NNODES / 32)   // 3125, exact

typedef __bf16 bf16x8 __attribute__((ext_vector_type(8)));
typedef float  f32x4  __attribute__((ext_vector_type(4)));

__device__ inline void split8(const float* s, bf16x8& h, bf16x8& l) {
#pragma unroll
    for (int j = 0; j < 8; ++j) {
        float v = s[j];
        __bf16 hh = (__bf16)v;
        h[j] = hh;
        l[j] = (__bf16)(v - (float)hh);
    }
}

// ===========================================================================
// CSR build (round-3 proven): histogram -> 3-kernel scan -> bucket fill
// ===========================================================================
__global__ __launch_bounds__(256) void hist_kernel(const int* __restrict__ dst,
                                                   int* __restrict__ counts, int nE) {
    int i = blockIdx.x * 256 + threadIdx.x;
    if (i < nE) atomicAdd(counts + dst[i], 1);
}

__global__ __launch_bounds__(256) void scan1_kernel(const int* __restrict__ counts,
                                                    int* __restrict__ bsum, int n) {
    __shared__ int s[256];
    int i = blockIdx.x * 256 + threadIdx.x;
    s[threadIdx.x] = (i < n) ? counts[i] : 0;
    __syncthreads();
    for (int off = 128; off > 0; off >>= 1) {
        if (threadIdx.x < off) s[threadIdx.x] += s[threadIdx.x + off];
        __syncthreads();
    }
    if (threadIdx.x == 0) bsum[blockIdx.x] = s[0];
}

__global__ __launch_bounds__(512) void scan2_kernel(int* __restrict__ bsum, int nb) {
    __shared__ int s[512];
    int t = threadIdx.x;
    int orig = (t < nb) ? bsum[t] : 0;
    s[t] = orig;
    __syncthreads();
    for (int off = 1; off < 512; off <<= 1) {
        int v = (t >= off) ? s[t - off] : 0;
        __syncthreads();
        s[t] += v;
        __syncthreads();
    }
    if (t < nb) bsum[t] = s[t] - orig;  // exclusive
}

// also zeroes counts so fill can reuse it as the running cursor
__global__ __launch_bounds__(256) void scan3_kernel(int* __restrict__ counts,
                                                    const int* __restrict__ boff,
                                                    int* __restrict__ rowptr, int n) {
    __shared__ int s[256];
    int i = blockIdx.x * 256 + threadIdx.x;
    int t = threadIdx.x;
    int orig = (i < n) ? counts[i] : 0;
    s[t] = orig;
    __syncthreads();
    for (int off = 1; off < 256; off <<= 1) {
        int v = (t >= off) ? s[t - off] : 0;
        __syncthreads();
        s[t] += v;
        __syncthreads();
    }
    if (i < n) {
        rowptr[i] = boff[blockIdx.x] + s[t] - orig;
        counts[i] = 0;
    }
    if (i == n - 1) rowptr[n] = boff[blockIdx.x] + s[t];
}

__global__ __launch_bounds__(256) void fill_kernel(const int* __restrict__ src,
                                                   const int* __restrict__ dst,
                                                   const int* __restrict__ rowptr,
                                                   int* __restrict__ cur,
                                                   int* __restrict__ eidx, int nE) {
    int i = blockIdx.x * 256 + threadIdx.x;
    if (i >= nE) return;
    int d = dst[i];
    int p = atomicAdd(cur + d, 1);
    eidx[rowptr[d] + p] = src[i];
}

// ===========================================================================
// Gather-mean + combine: out = base + mean_nbr hi(nbr), re-split to hi/lo.
// One wave/node; 4 edges in parallel (16 lanes x bf16x8 per edge row).
// ===========================================================================
__global__ __launch_bounds__(256) void gather_kernel(const __bf16* __restrict__ Hhi,
                                                     const __bf16* __restrict__ Hlo,
                                                     const int* __restrict__ rowptr,
                                                     const int* __restrict__ eidx,
                                                     __bf16* __restrict__ Ohi,
                                                     __bf16* __restrict__ Olo, int n) {
    int node = blockIdx.x * 4 + (threadIdx.x >> 6);
    int lane = threadIdx.x & 63;
    if (node >= n) return;
    int g = lane >> 4, p = lane & 15;
    int e0 = rowptr[node], e1 = rowptr[node + 1];
    float acc[8] = {0.f, 0.f, 0.f, 0.f, 0.f, 0.f, 0.f, 0.f};
    for (int j = e0; j < e1; j += 4) {
        int na = e1 - j;
        int sid = (lane < na && lane < 4) ? eidx[j + lane] : -1;
        int s = __shfl(sid, g);
        if (s >= 0) {
            bf16x8 v = *(const bf16x8*)(Hhi + (size_t)s * 128 + p * 8);
#pragma unroll
            for (int r = 0; r < 8; ++r) acc[r] += (float)v[r];
        }
    }
#pragma unroll
    for (int r = 0; r < 8; ++r) {
        acc[r] += __shfl_xor(acc[r], 16);
        acc[r] += __shfl_xor(acc[r], 32);
    }
    if (g == 0) {
        float rinv = 1.0f / fmaxf((float)(e1 - e0), 1.0f);
        bf16x8 bh = *(const bf16x8*)(Hhi + (size_t)node * 128 + p * 8);
        bf16x8 bl = *(const bf16x8*)(Hlo + (size_t)node * 128 + p * 8);
        bf16x8 oh, ol;
#pragma unroll
        for (int r = 0; r < 8; ++r) {
            float v = (float)bh[r] + (float)bl[r] + acc[r] * rinv;
            __bf16 h = (__bf16)v;
            oh[r] = h;
            ol[r] = (__bf16)(v - (float)h);
        }
        *(bf16x8*)(Ohi + (size_t)node * 128 + p * 8) = oh;
        *(bf16x8*)(Olo + (size_t)node * 128 + p * 8) = ol;
    }
}

// ===========================================================================
// Fused GEMM chain: up to 3 stages of out = act(in @ W^T + b), 128 cols each
// (last stage optionally 64 cols -> f32 d_out). 512 thr = 8 waves; 32-row
// tile/block; wave w owns n-slice [16w,16w+16); W hi/lo register-resident
// (split from f32 in-kernel); inter-stage h via LDS as pre-split hi/lo bf16.
// MFMA 16x16x32_bf16, 3-term split product (hi*hi + lo*hi + hi*lo).
// A-frag: row=lane&15, k=(lane>>4)*8+j (A/B same k-map). C/D: col=lane&15,
// row=(lane>>4)*4+reg  [m89-verified; round-4 proven].
// ===========================================================================
#define DO_MFMA_SET(SIDX, AH, AL, A0)                                                        \
    {                                                                                        \
        f32x4 a_ = {A0, A0, A0, A0};                                                         \
        _Pragma("unroll") for (int ks = 0; ks < 4; ++ks) {                                   \
            a_ = __builtin_amdgcn_mfma_f32_16x16x32_bf16(AH[ks], whi[SIDX][ks], a_, 0, 0, 0);\
            a_ = __builtin_amdgcn_mfma_f32_16x16x32_bf16(AL[ks], whi[SIDX][ks], a_, 0, 0, 0);\
            a_ = __builtin_amdgcn_mfma_f32_16x16x32_bf16(AH[ks], wlo[SIDX][ks], a_, 0, 0, 0);\
        }                                                                                    \
        acc[st] = a_;                                                                        \
    }

#define DO_STAGE_HBUF(SIDX)                                                                  \
    {                                                                                        \
        _Pragma("unroll") for (int st = 0; st < 2; ++st) {                                   \
            bf16x8 ah[4], al[4];                                                             \
            _Pragma("unroll") for (int ks = 0; ks < 4; ++ks) {                               \
                ah[ks] = *(const bf16x8*)&hb_hi[st][lm][ks * 32 + lk];                       \
                al[ks] = *(const bf16x8*)&hb_lo[st][lm][ks * 32 + lk];                       \
            }                                                                                \
            DO_MFMA_SET(SIDX, ah, al, bval[SIDX]);                                           \
        }                                                                                    \
    }

#define DO_STORE_HBUF(RELU_)                                                                 \
    __syncthreads();                                                                         \
    {                                                                                        \
        _Pragma("unroll") for (int st = 0; st < 2; ++st) {                                   \
            _Pragma("unroll") for (int r = 0; r < 4; ++r) {                                  \
                float v_ = acc[st][r];                                                       \
                if (RELU_) v_ = fmaxf(v_, 0.f);                                              \
                __bf16 h_ = (__bf16)v_;                                                      \
                hb_hi[st][g * 4 + r][w * 16 + lm] = h_;                                      \
                hb_lo[st][g * 4 + r][w * 16 + lm] = (__bf16)(v_ - (float)h_);                \
            }                                                                                \
        }                                                                                    \
    }                                                                                        \
    __syncthreads();

template <int S, bool INF32, bool R0, bool R1, bool R2, bool LAST64>
__global__ __launch_bounds__(512) void chain_kernel(const void* __restrict__ Ah_,
                                                    const void* __restrict__ Al_,
                                                    const float* __restrict__ Wg0,
                                                    const float* __restrict__ Bg0,
                                                    const float* __restrict__ Wg1,
                                                    const float* __restrict__ Bg1,
                                                    const float* __restrict__ Wg2,
                                                    const float* __restrict__ Bg2,
                                                    __bf16* __restrict__ Ohi,
                                                    __bf16* __restrict__ Olo,
                                                    float* __restrict__ Of32, int nt32) {
    __shared__ __align__(16) __bf16 hb_hi[2][16][136];
    __shared__ __align__(16) __bf16 hb_lo[2][16][136];
    const int tid = threadIdx.x;
    const int lane = tid & 63, w = tid >> 6;
    const int lm = lane & 15, g = lane >> 4, lk = g * 8;

    // --- weight fragments: split f32 -> hi/lo in registers ---
    bf16x8 whi[3][4], wlo[3][4];
    float bval[3];
    const float* Wp[3] = {Wg0, Wg1, Wg2};
    const float* Bp[3] = {Bg0, Bg1, Bg2};
#pragma unroll
    for (int s = 0; s < S; ++s) {
        int n = ((LAST64 && s == S - 1) ? (w & 3) : w) * 16 + lm;
        bval[s] = Bp[s][n];
#pragma unroll
        for (int ks = 0; ks < 4; ++ks) {
            float t_[8];
            const float* src = Wp[s] + (size_t)n * 128 + ks * 32 + lk;
            *(float4*)t_ = *(const float4*)src;
            *(float4*)(t_ + 4) = *(const float4*)(src + 4);
            split8(t_, whi[s][ks], wlo[s][ks]);
        }
    }

    for (int t32 = blockIdx.x; t32 < nt32; t32 += gridDim.x) {
        const int row0 = t32 * 32;
        f32x4 acc[2];

        // ---- stage 0 (input from global) ----
#pragma unroll
        for (int st = 0; st < 2; ++st) {
            bf16x8 ah[4], al[4];
            if (INF32) {
                const float* base_ = (const float*)Ah_ + (size_t)(row0 + st * 16 + lm) * 128;
#pragma unroll
                for (int ks = 0; ks < 4; ++ks) {
                    float t_[8];
                    *(float4*)t_ = *(const float4*)(base_ + ks * 32 + lk);
                    *(float4*)(t_ + 4) = *(const float4*)(base_ + ks * 32 + lk + 4);
                    split8(t_, ah[ks], al[ks]);
                }
            } else {
                const __bf16* bh_ = (const __bf16*)Ah_ + (size_t)(row0 + st * 16 + lm) * 128;
                const __bf16* bl_ = (const __bf16*)Al_ + (size_t)(row0 + st * 16 + lm) * 128;
#pragma unroll
                for (int ks = 0; ks < 4; ++ks) {
                    ah[ks] = *(const bf16x8*)(bh_ + ks * 32 + lk);
                    al[ks] = *(const bf16x8*)(bl_ + ks * 32 + lk);
                }
            }
            DO_MFMA_SET(0, ah, al, bval[0]);
        }
        DO_STORE_HBUF(R0);

        // ---- stage 1 ----
        DO_STAGE_HBUF(1);
        if constexpr (S == 2) {
            DO_STORE_HBUF(R1);
        } else {
            DO_STORE_HBUF(R1);
            // ---- stage 2 ----
            DO_STAGE_HBUF(2);
            if constexpr (LAST64) {
                if (w < 4) {
#pragma unroll
                    for (int st = 0; st < 2; ++st)
#pragma unroll
                        for (int r = 0; r < 4; ++r) {
                            int m = row0 + st * 16 + g * 4 + r;
                            Of32[(size_t)m * 64 + w * 16 + lm] = acc[st][r];
                        }
                }
                continue;  // no hbuf store / readback
            } else {
                DO_STORE_HBUF(R2);
            }
        }

        // ---- cooperative readback: hbuf -> bf16 hi/lo planes ----
        {
            int row = tid >> 4;
            int cc = (tid & 15) * 8;
            bf16x8 hh = *(const bf16x8*)&hb_hi[row >> 4][row & 15][cc];
            bf16x8 ll = *(const bf16x8*)&hb_lo[row >> 4][row & 15][cc];
            size_t off = (size_t)(row0 + row) * 128 + cc;
            *(bf16x8*)(Ohi + off) = hh;
            *(bf16x8*)(Olo + off) = ll;
        }
    }
}

// ===========================================================================
extern "C" void kernel_launch(void* const* d_in, const int* in_sizes, int n_in,
                              void* d_out, int out_size, void* d_ws, size_t ws_size,
                              hipStream_t stream) {
    const float* x   = (const float*)d_in[0];
    const int*   src = (const int*)d_in[1];
    const int*   dst = (const int*)d_in[2];
    const float* W1  = (const float*)d_in[3];
    const float* b1  = (const float*)d_in[4];
    const float* W2  = (const float*)d_in[5];
    const float* b2  = (const float*)d_in[6];
    const float* W3  = (const float*)d_in[7];
    const float* b3  = (const float*)d_in[8];
    const float* Wo1 = (const float*)d_in[9];
    const float* bo1 = (const float*)d_in[10];
    const float* Wo2 = (const float*)d_in[11];
    const float* bo2 = (const float*)d_in[12];
    float* out = (float*)d_out;

    const size_t PLANE = (size_t)NNODES * 128 * sizeof(__bf16);  // 25.6 MB
    char* ws = (char*)d_ws;
    __bf16* P0h = (__bf16*)ws;
    __bf16* P0l = (__bf16*)(ws + PLANE);
    __bf16* P1h = (__bf16*)(ws + 2 * PLANE);
    __bf16* P1l = (__bf16*)(ws + 3 * PLANE);
    char* p = ws + 4 * PLANE;
    int* counts = (int*)p;  p += 512 * 1024;
    int* rowptr = (int*)p;  p += 512 * 1024;
    int* bsum   = (int*)p;  p += 16 * 1024;
    int* eidx   = (int*)p;  // 3.2 MB

    dim3 blk(256);
    const int NB = (NNODES + 255) / 256;  // 391
    const int ge = (NEDGES + 255) / 256;  // 3125
    const int gg = (NNODES + 3) / 4;      // 25000
    const int GC = 1563;                  // chain grid (512 thr)

    // ---- CSR build (dst-indexed) ----
    hipMemsetAsync(counts, 0, NNODES * sizeof(int), stream);
    hist_kernel<<<ge, blk, 0, stream>>>(dst, counts, NEDGES);
    scan1_kernel<<<NB, blk, 0, stream>>>(counts, bsum, NNODES);
    scan2_kernel<<<1, 512, 0, stream>>>(bsum, NB);
    scan3_kernel<<<NB, blk, 0, stream>>>(counts, bsum, rowptr, NNODES);
    fill_kernel<<<ge, blk, 0, stream>>>(src, dst, rowptr, counts, eidx, NEDGES);

    // ---- chain A: x2 = lin2(relu(lin1(x))) ----
    chain_kernel<2, true, true, false, false, false><<<GC, 512, 0, stream>>>(
        x, nullptr, W1, b1, W2, b2, nullptr, nullptr, P0h, P0l, nullptr, NT32);

    // ---- h = x2 + mean_agg(x2) ----
    gather_kernel<<<gg, blk, 0, stream>>>(P0h, P0l, rowptr, eidx, P1h, P1l, NNODES);

    // ---- chain B: h3 = relu(lin3(lin2(relu(lin1(h))))) ----
    chain_kernel<3, false, true, false, true, false><<<GC, 512, 0, stream>>>(
        P1h, P1l, W1, b1, W2, b2, W3, b3, P0h, P0l, nullptr, NT32);

    // ---- h4 = h3 + mean_agg(h3) ----
    gather_kernel<<<gg, blk, 0, stream>>>(P0h, P0l, rowptr, eidx, P1h, P1l, NNODES);

    // ---- chain C: out = lino2(relu(lino1(relu(lin3(h4))))) ----
    chain_kernel<3, false, true, true, false, true><<<GC, 512, 0, stream>>>(
        P1h, P1l, W3, b3, Wo1, bo1, Wo2, bo2, nullptr, nullptr, out, NT32);
}